// Round 1
// baseline (6213.873 us; speedup 1.0000x reference)
//
#include <hip/hip_runtime.h>
#include <hip/hip_bf16.h>
#include <math.h>

typedef unsigned short u16;
typedef __attribute__((ext_vector_type(8))) short short8;
typedef __attribute__((ext_vector_type(4))) float f32x4;

__device__ __forceinline__ u16 f2bf(float f) {
  union { float f; unsigned u; } v; v.f = f;
  unsigned r = v.u + 0x7fffu + ((v.u >> 16) & 1u);
  return (u16)(r >> 16);
}

// ---------------------------------------------------------------------------
// GEMM: C(M,N) = act(A(M,K) @ Bt(N,K)^T + bias)
// A bf16: if !ATRANS row-major (M,K) w/ lda; if ATRANS stored (K,M) row-major
//         (lda = k-row stride), logical A[m][k] = st[k*lda + m].
// Bt bf16 row-major (N,K), ldb.
// MODE 0: bf16 store (no bias). MODE 1: fp32 sigmoid(x+bias). MODE 2: fp32 tanh(x+bias).
// Requires: M % BM == 0, N % BN == 0, K % 32 == 0 (callers guarantee).
// MFMA 16x16x32 bf16 layouts: A/B: lane holds row/col = lane&15,
// k = (lane>>4)*8 + e (e=0..7 contiguous). D: col = lane&15, row = (lane>>4)*4 + reg.
// ---------------------------------------------------------------------------
template<int BM, int BN, int WR, int WC, bool ATRANS, int MODE>
__global__ __launch_bounds__(256) void gemm_nt(
    const u16* __restrict__ A, long sAb, int lda,
    const u16* __restrict__ Bt, long sBb, int ldb,
    void* __restrict__ Cp, long sCb, int ldc,
    const float* __restrict__ bias, int K)
{
  constexpr int BK = 32;
  constexpr int FM = BM / (WR * 16);
  constexpr int FN = BN / (WC * 16);
  __shared__ u16 As[BM * BK];
  __shared__ u16 Bs[BN * BK];
  const int tid = threadIdx.x;
  const int lane = tid & 63, wid = tid >> 6;
  const int wr = wid / WC, wc = wid % WC;
  const int l15 = lane & 15, l4 = lane >> 4;
  const int m0 = blockIdx.x * BM, n0 = blockIdx.y * BN;
  const long b = blockIdx.z;
  const u16* Ab = A + b * sAb;
  const u16* Bb = Bt + b * sBb;

  f32x4 acc[FM][FN] = {};

  for (int k0 = 0; k0 < K; k0 += BK) {
    if constexpr (!ATRANS) {
      for (int cid = tid; cid < BM * 4; cid += 256) {
        int m = cid >> 2, kc = cid & 3;
        *(short8*)&As[m * BK + kc * 8] =
            *(const short8*)(Ab + (long)(m0 + m) * lda + k0 + kc * 8);
      }
    } else {
      for (int cid = tid; cid < BM * 4; cid += 256) {
        int m = cid % BM, kc = cid / BM;
        const u16* src = Ab + (long)(k0 + kc * 8) * lda + (m0 + m);
        short8 v;
        #pragma unroll
        for (int j = 0; j < 8; j++) v[j] = (short)src[(long)j * lda];
        *(short8*)&As[m * BK + kc * 8] = v;
      }
    }
    for (int cid = tid; cid < BN * 4; cid += 256) {
      int n = cid >> 2, kc = cid & 3;
      *(short8*)&Bs[n * BK + kc * 8] =
          *(const short8*)(Bb + (long)(n0 + n) * ldb + k0 + kc * 8);
    }
    __syncthreads();
    short8 af[FM], bf[FN];
    #pragma unroll
    for (int i = 0; i < FM; i++)
      af[i] = *(const short8*)&As[(wr * FM * 16 + i * 16 + l15) * BK + l4 * 8];
    #pragma unroll
    for (int j = 0; j < FN; j++)
      bf[j] = *(const short8*)&Bs[(wc * FN * 16 + j * 16 + l15) * BK + l4 * 8];
    #pragma unroll
    for (int i = 0; i < FM; i++)
      #pragma unroll
      for (int j = 0; j < FN; j++)
        acc[i][j] = __builtin_amdgcn_mfma_f32_16x16x32_bf16(af[i], bf[j], acc[i][j], 0, 0, 0);
    __syncthreads();
  }

  #pragma unroll
  for (int i = 0; i < FM; i++) {
    #pragma unroll
    for (int j = 0; j < FN; j++) {
      int mbase = m0 + wr * FM * 16 + i * 16 + l4 * 4;
      int n = n0 + wc * FN * 16 + j * 16 + l15;
      #pragma unroll
      for (int r = 0; r < 4; r++) {
        float v = acc[i][j][r];
        long off = (long)(mbase + r) * ldc + n;
        if constexpr (MODE == 0) {
          ((u16*)Cp)[b * sCb + off] = f2bf(v);
        } else if constexpr (MODE == 1) {
          float x = v + bias[n];
          ((float*)Cp)[b * sCb + off] = 1.f / (1.f + expf(-x));
        } else {
          float x = v + bias[n];
          ((float*)Cp)[b * sCb + off] = tanhf(x);
        }
      }
    }
  }
}

// ---------------------------------------------------------------------------
// Build channel-major z slice 0: z^T[b][ch][n] = ch < Cx ? x[b,n,ch]
//                                               : h[b,n,ch-Cx] * (r ? r[b,n,ch-Cx] : 1)
// x: fp32, addr = b*xbs + n*xs + ch. h: (B,512,H) fp32. r: gates (B,512,2H), r-part = cols [0,H).
// ---------------------------------------------------------------------------
__global__ __launch_bounds__(256) void concat_cm(
    const float* __restrict__ x, int xbs, int xs, int Cx,
    const float* __restrict__ h, const float* __restrict__ r,
    u16* __restrict__ z, long zbs, int H)
{
  int n = blockIdx.x * 256 + threadIdx.x;   // 0..511
  int ch = blockIdx.y;
  int b = blockIdx.z;
  long row = (long)b * 512 + n;
  float v;
  if (ch < Cx) {
    v = x[(long)b * xbs + (long)n * xs + ch];
  } else {
    int c = ch - Cx;
    v = h[row * H + c];
    if (r) v *= r[row * (2 * H) + c];
  }
  z[(long)b * zbs + (long)ch * 512 + n] = f2bf(v);
}

// ---------------------------------------------------------------------------
// Fused GRU update + LayerNorm over H=128. One block (128 thr) per (b,n) row.
// h <- LN((1-u)*h + u*c) * gamma + beta
// ---------------------------------------------------------------------------
__global__ __launch_bounds__(128) void gru_ln(
    const float* __restrict__ gates, const float* __restrict__ cand,
    float* __restrict__ h, const float* __restrict__ gamma,
    const float* __restrict__ beta)
{
  long row = blockIdx.x;
  int t = threadIdx.x;
  float u = gates[row * 256 + 128 + t];
  float c = cand[row * 128 + t];
  float hv = h[row * 128 + t];
  float hn = (1.f - u) * hv + u * c;
  float s = hn, s2 = hn * hn;
  #pragma unroll
  for (int o = 32; o > 0; o >>= 1) {
    s += __shfl_xor(s, o);
    s2 += __shfl_xor(s2, o);
  }
  __shared__ float red[4];
  int w = t >> 6;
  if ((t & 63) == 0) { red[w] = s; red[2 + w] = s2; }
  __syncthreads();
  float S = red[0] + red[1], S2 = red[2] + red[3];
  float mu = S * (1.f / 128.f);
  float var = S2 * (1.f / 128.f) - mu * mu;
  float o = (hn - mu) * rsqrtf(var + 1e-5f) * gamma[t] + beta[t];
  h[row * 128 + t] = o;
}

// ---------------------------------------------------------------------------
__global__ void cvt_bf16(const float* __restrict__ s, u16* __restrict__ d, int n) {
  int i = blockIdx.x * 256 + threadIdx.x;
  if (i < n) d[i] = f2bf(s[i]);
}
// W (Ksrc, Nout) fp32 -> Wt (Nout, Kpad) bf16, zero-pad k >= Ksrc.
__global__ void wt_cvt(const float* __restrict__ W, u16* __restrict__ Wt,
                       int Ksrc, int Kpad, int Nout) {
  long idx = (long)blockIdx.x * 256 + threadIdx.x;
  if (idx >= (long)Nout * Kpad) return;
  int o = (int)(idx / Kpad), k = (int)(idx % Kpad);
  Wt[idx] = f2bf(k < Ksrc ? W[(long)k * Nout + o] : 0.f);
}

// ---------------------------------------------------------------------------
extern "C" void kernel_launch(void* const* d_in, const int* in_sizes, int n_in,
                              void* d_out, int out_size, void* d_ws, size_t ws_size,
                              hipStream_t stream) {
  const float* x_seq = (const float*)d_in[0];
  const float* Tf  = (const float*)d_in[1];
  const float* Tb  = (const float*)d_in[2];
  const float* Wg0 = (const float*)d_in[3];
  const float* bg0 = (const float*)d_in[4];
  const float* Wc0 = (const float*)d_in[5];
  const float* bc0 = (const float*)d_in[6];
  const float* g0  = (const float*)d_in[7];
  const float* be0 = (const float*)d_in[8];
  const float* Wg1 = (const float*)d_in[9];
  const float* bg1 = (const float*)d_in[10];
  const float* Wc1 = (const float*)d_in[11];
  const float* bc1 = (const float*)d_in[12];
  const float* g1  = (const float*)d_in[13];
  const float* be1 = (const float*)d_in[14];

  constexpr int B = 32, T = 8, N = 512, F = 16, H = 128;
  constexpr long NB = (long)B * N;

  char* w = (char*)d_ws;
  u16* z = (u16*)w;           w += (long)B * 1792 * 512 * 2;   // shared z (both layers)
  float* gates = (float*)w;   w += (long)B * 512 * 256 * 4;
  float* cand = (float*)w;    w += (long)B * 512 * 128 * 4;
  u16* Tfb = (u16*)w;         w += 512L * 512 * 2;
  u16* Tbb = (u16*)w;         w += 512L * 512 * 2;
  u16* Wg0t = (u16*)w;        w += 256L * 1024 * 2;
  u16* Wc0t = (u16*)w;        w += 128L * 1024 * 2;
  u16* Wg1t = (u16*)w;        w += 256L * 1792 * 2;
  u16* Wc1t = (u16*)w;        w += 128L * 1792 * 2;

  float* h0 = (float*)d_out;
  float* h1 = h0 + NB * H;

  hipMemsetAsync(d_out, 0, (size_t)out_size * 4, stream);
  hipMemsetAsync(z, 0, (size_t)B * 1792 * 512 * 2, stream);  // guard vs NaN bits on 1st call

  cvt_bf16<<<(512 * 512 + 255) / 256, 256, 0, stream>>>(Tf, Tfb, 512 * 512);
  cvt_bf16<<<(512 * 512 + 255) / 256, 256, 0, stream>>>(Tb, Tbb, 512 * 512);
  wt_cvt<<<(256 * 1024 + 255) / 256, 256, 0, stream>>>(Wg0, Wg0t, 1008, 1024, 256);
  wt_cvt<<<(128 * 1024 + 255) / 256, 256, 0, stream>>>(Wc0, Wc0t, 1008, 1024, 128);
  wt_cvt<<<(256 * 1792 + 255) / 256, 256, 0, stream>>>(Wg1, Wg1t, 1792, 1792, 256);
  wt_cvt<<<(128 * 1792 + 255) / 256, 256, 0, stream>>>(Wc1, Wc1t, 1792, 1792, 128);

  static const int prev[6] = {0, 1, 2, 0, 4, 5};

  for (int t = 0; t < T; t++) {
    // -------- layer 0: C = 144 (F + H), Kpad = 1024 --------
    {
      const int C = 144, Kpad = 1024;
      const long zbs = (long)Kpad * 512;
      const float* xt = x_seq + (long)t * N * F;
      const int xbs = T * N * F, xs = F;
      auto diff6 = [&]() {
        for (int s = 0; s < 6; s++) {
          const u16* Tm = (s < 3) ? Tfb : Tbb;
          gemm_nt<48, 128, 1, 4, false, 0><<<dim3(3, 4, B), 256, 0, stream>>>(
              z + (long)prev[s] * C * 512, zbs, 512, Tm, 0, 512,
              (void*)(z + (long)(s + 1) * C * 512), zbs, 512, nullptr, 512);
        }
      };
      concat_cm<<<dim3(2, C, B), 256, 0, stream>>>(xt, xbs, xs, F, h0, nullptr, z, zbs, H);
      diff6();
      gemm_nt<128, 128, 2, 2, true, 1><<<dim3(4, 2, B), 256, 0, stream>>>(
          z, zbs, 512, Wg0t, 0, Kpad, gates, (long)512 * 256, 256, bg0, Kpad);
      concat_cm<<<dim3(2, C, B), 256, 0, stream>>>(xt, xbs, xs, F, h0, gates, z, zbs, H);
      diff6();
      gemm_nt<64, 128, 2, 2, true, 2><<<dim3(8, 1, B), 256, 0, stream>>>(
          z, zbs, 512, Wc0t, 0, Kpad, cand, (long)512 * 128, 128, bc0, Kpad);
      gru_ln<<<NB, 128, 0, stream>>>(gates, cand, h0, g0, be0);
    }
    // -------- layer 1: C = 256 (H + H), Kpad = 1792 --------
    {
      const int C = 256, Kpad = 1792;
      const long zbs = (long)Kpad * 512;
      auto diff6 = [&]() {
        for (int s = 0; s < 6; s++) {
          const u16* Tm = (s < 3) ? Tfb : Tbb;
          gemm_nt<128, 128, 2, 2, false, 0><<<dim3(2, 4, B), 256, 0, stream>>>(
              z + (long)prev[s] * C * 512, zbs, 512, Tm, 0, 512,
              (void*)(z + (long)(s + 1) * C * 512), zbs, 512, nullptr, 512);
        }
      };
      concat_cm<<<dim3(2, C, B), 256, 0, stream>>>(h0, 512 * 128, 128, H, h1, nullptr, z, zbs, H);
      diff6();
      gemm_nt<128, 128, 2, 2, true, 1><<<dim3(4, 2, B), 256, 0, stream>>>(
          z, zbs, 512, Wg1t, 0, Kpad, gates, (long)512 * 256, 256, bg1, Kpad);
      concat_cm<<<dim3(2, C, B), 256, 0, stream>>>(h0, 512 * 128, 128, H, h1, gates, z, zbs, H);
      diff6();
      gemm_nt<64, 128, 2, 2, true, 2><<<dim3(8, 1, B), 256, 0, stream>>>(
          z, zbs, 512, Wc1t, 0, Kpad, cand, (long)512 * 128, 128, bc1, Kpad);
      gru_ln<<<NB, 128, 0, stream>>>(gates, cand, h1, g1, be1);
    }
  }
}

// Round 2
// 4010.746 us; speedup vs baseline: 1.5493x; 1.5493x over previous
//
#include <hip/hip_runtime.h>
#include <hip/hip_bf16.h>
#include <math.h>

typedef unsigned short u16;
typedef __attribute__((ext_vector_type(8))) short short8;
typedef __attribute__((ext_vector_type(4))) float f32x4;

__device__ __forceinline__ u16 f2bf(float f) {
  union { float f; unsigned u; } v; v.f = f;
  unsigned r = v.u + 0x7fffu + ((v.u >> 16) & 1u);
  return (u16)(r >> 16);
}

// async global->LDS, 16B per lane. LDS dest must be wave-uniform base; HW adds lane*16.
__device__ __forceinline__ void glds16(const u16* g, u16* l) {
  __builtin_amdgcn_global_load_lds(
      (const __attribute__((address_space(1))) void*)g,
      (__attribute__((address_space(3))) void*)l, 16, 0, 0);
}

// ---------------------------------------------------------------------------
// Diffusion GEMM (pair-fused Tf/Tb chains): C[ch][n] = sum_k A[ch][k] * T[n][k]
// A: channel-major slice (M rows x 512), T: (512,512) row-major bf16. K=N=512.
// grid.z = 2*B: chain = z&1 (0=Tf,1=Tb), b = z>>1. A += chain?aoff:0, C += chain?coff:0.
// Staging: global_load_lds width 16 for both tiles (linear LDS, conflict-free frag reads).
// ---------------------------------------------------------------------------
template<int BM, int BN, int WR, int WC>
__global__ __launch_bounds__(256) void gemm_diff(
    const u16* __restrict__ A, long sAb, long aoff,
    u16* __restrict__ C, long sCb, long coff,
    const u16* __restrict__ Tfm, const u16* __restrict__ Tbm)
{
  constexpr int BK = 32;
  constexpr int FM = BM / (WR * 16);
  constexpr int FN = BN / (WC * 16);
  constexpr int SLOTS = (BM + BN) * 4;   // 16B slots per K-tile
  __shared__ u16 sm[(BM + BN) * BK];
  const int tid = threadIdx.x, lane = tid & 63;
  const int wid = tid >> 6, wr = wid / WC, wc = wid % WC;
  const int l15 = lane & 15, l4 = lane >> 4;
  const int m0 = blockIdx.x * BM, n0 = blockIdx.y * BN;
  const int chain = blockIdx.z & 1;
  const long b = blockIdx.z >> 1;
  const u16* Ab = A + b * sAb + (chain ? aoff : 0);
  const u16* Bt = chain ? Tbm : Tfm;
  u16* Cb = C + b * sCb + (chain ? coff : 0);

  f32x4 acc[FM][FN] = {};

  for (int k0 = 0; k0 < 512; k0 += BK) {
    for (int s = tid; s < SLOTS; s += 256) {
      const u16* gp;
      if (s < BM * 4) { int m = s >> 2, kc = s & 3; gp = Ab + (long)(m0 + m) * 512 + k0 + kc * 8; }
      else { int q = s - BM * 4; int n = q >> 2, kc = q & 3; gp = Bt + (long)(n0 + n) * 512 + k0 + kc * 8; }
      glds16(gp, sm + (s - lane) * 8);
    }
    __syncthreads();
    short8 af[FM], bf[FN];
    #pragma unroll
    for (int i = 0; i < FM; i++)
      af[i] = *(const short8*)&sm[(wr * FM * 16 + i * 16 + l15) * BK + l4 * 8];
    #pragma unroll
    for (int j = 0; j < FN; j++)
      bf[j] = *(const short8*)&sm[BM * BK + (wc * FN * 16 + j * 16 + l15) * BK + l4 * 8];
    #pragma unroll
    for (int i = 0; i < FM; i++)
      #pragma unroll
      for (int j = 0; j < FN; j++)
        acc[i][j] = __builtin_amdgcn_mfma_f32_16x16x32_bf16(af[i], bf[j], acc[i][j], 0, 0, 0);
    __syncthreads();
  }

  #pragma unroll
  for (int i = 0; i < FM; i++) {
    #pragma unroll
    for (int j = 0; j < FN; j++) {
      int mb = m0 + wr * FM * 16 + i * 16 + l4 * 4;
      int n = n0 + wc * FN * 16 + j * 16 + l15;
      #pragma unroll
      for (int r = 0; r < 4; r++)
        Cb[(long)(mb + r) * 512 + n] = f2bf(acc[i][j][r]);
    }
  }
}

// ---------------------------------------------------------------------------
// Projection GEMM: out(M=512 nodes, N) = act(z(M,K) @ Wt(N,K)^T + bias)
// z logical A[m][k] read from two channel-major buffers: k<Crows -> A0[k][m],
// else A1[k-Crows][m] (stride 512). Wt staged via global_load_lds; A gathered
// into XOR-swizzled LDS (byte ^= (m&7)<<4) for conflict-free ds ops.
// MODE 1 (gates): sigmoid; cols<128 -> write r*h transposed bf16 to t0cH,
//                 cols>=128 -> write u fp32 to out (B,512,128).
// MODE 2 (cand):  tanh -> out (B,512,128) fp32.
// ---------------------------------------------------------------------------
template<int BM, int BN, int WR, int WC, int MODE>
__global__ __launch_bounds__(256) void gemm_proj(
    const u16* __restrict__ A0, long sA0, int Crows,
    const u16* __restrict__ A1, long sA1,
    const u16* __restrict__ Bt, int ldb, int K,
    const float* __restrict__ bias,
    const float* __restrict__ hst,
    u16* __restrict__ t0cH, long st0c,
    float* __restrict__ out)
{
  constexpr int BK = 32;
  constexpr int FM = BM / (WR * 16);
  constexpr int FN = BN / (WC * 16);
  __shared__ u16 As[BM * BK];
  __shared__ u16 Bs[BN * BK];
  const int tid = threadIdx.x, lane = tid & 63;
  const int wid = tid >> 6, wr = wid / WC, wc = wid % WC;
  const int l15 = lane & 15, l4 = lane >> 4;
  const int m0 = blockIdx.x * BM, n0 = blockIdx.y * BN;
  const long b = blockIdx.z;
  const u16* A0b = A0 + b * sA0;
  const u16* A1b = A1 + b * sA1;

  f32x4 acc[FM][FN] = {};

  for (int k0 = 0; k0 < K; k0 += BK) {
    // B tile: async direct-to-LDS (rows K-contiguous)
    for (int s = tid; s < BN * 4; s += 256) {
      int n = s >> 2, kc = s & 3;
      glds16(Bt + (long)(n0 + n) * ldb + k0 + kc * 8, Bs + (s - lane) * 8);
    }
    // A tile: transposed gather (coalesced 2B per lane), swizzled LDS write
    for (int cid = tid; cid < BM * 4; cid += 256) {
      int m = cid & (BM - 1), kc = cid / BM;
      short8 v;
      #pragma unroll
      for (int j = 0; j < 8; j++) {
        int k = k0 + kc * 8 + j;
        v[j] = (short)((k < Crows) ? A0b[(long)k * 512 + m0 + m]
                                   : A1b[(long)(k - Crows) * 512 + m0 + m]);
      }
      *(short8*)&As[(m * BK + kc * 8) ^ ((m & 7) << 3)] = v;
    }
    __syncthreads();
    short8 af[FM], bf[FN];
    #pragma unroll
    for (int i = 0; i < FM; i++) {
      int row = wr * FM * 16 + i * 16 + l15;
      af[i] = *(const short8*)&As[(row * BK + l4 * 8) ^ ((row & 7) << 3)];
    }
    #pragma unroll
    for (int j = 0; j < FN; j++)
      bf[j] = *(const short8*)&Bs[(wc * FN * 16 + j * 16 + l15) * BK + l4 * 8];
    #pragma unroll
    for (int i = 0; i < FM; i++)
      #pragma unroll
      for (int j = 0; j < FN; j++)
        acc[i][j] = __builtin_amdgcn_mfma_f32_16x16x32_bf16(af[i], bf[j], acc[i][j], 0, 0, 0);
    __syncthreads();
  }

  #pragma unroll
  for (int i = 0; i < FM; i++) {
    #pragma unroll
    for (int j = 0; j < FN; j++) {
      int mb = m0 + wr * FM * 16 + i * 16 + l4 * 4;
      int n = n0 + wc * FN * 16 + j * 16 + l15;
      #pragma unroll
      for (int r = 0; r < 4; r++) {
        float v = acc[i][j][r] + bias[n];
        long node = mb + r;
        if constexpr (MODE == 1) {
          float g = 1.f / (1.f + expf(-v));
          if (n < 128) {
            float rh = g * hst[(b * 512 + node) * 128 + n];
            t0cH[b * st0c + (long)n * 512 + node] = f2bf(rh);
          } else {
            out[(b * 512 + node) * 128 + (n - 128)] = g;
          }
        } else {
          out[(b * 512 + node) * 128 + n] = tanhf(v);
        }
      }
    }
  }
}

// ---------------------------------------------------------------------------
// Fused GRU update + LayerNorm; also writes h^T (bf16, channel-major) into up
// to 3 term-0 targets (next-step gates input / next-layer x-parts).
// Block: 64 nodes x 128 ch, grid (8, B).
// ---------------------------------------------------------------------------
__global__ __launch_bounds__(256) void gru_ln2(
    const float* __restrict__ ub, const float* __restrict__ cd,
    float* __restrict__ h, const float* __restrict__ gamma, const float* __restrict__ beta,
    u16* __restrict__ t1, long s1, int o1,
    u16* __restrict__ t2, long s2, int o2,
    u16* __restrict__ t3, long s3, int o3)
{
  __shared__ float hs[64][132];
  const int tid = threadIdx.x;
  const long b = blockIdx.y;
  const int n0 = blockIdx.x * 64;
  const long rbase = (b * 512 + n0) * 128;

  #pragma unroll
  for (int i = 0; i < 32; i++) {
    int idx = tid + i * 256;
    float u = ub[rbase + idx];
    float cc = cd[rbase + idx];
    float hv = h[rbase + idx];
    hs[idx >> 7][idx & 127] = (1.f - u) * hv + u * cc;
  }
  __syncthreads();

  const int r = tid >> 2, sub = tid & 3;
  float s = 0.f, s2v = 0.f;
  #pragma unroll
  for (int i = 0; i < 32; i++) {
    float v = hs[r][sub + 4 * i];
    s += v; s2v += v * v;
  }
  s += __shfl_xor(s, 1); s2v += __shfl_xor(s2v, 1);
  s += __shfl_xor(s, 2); s2v += __shfl_xor(s2v, 2);
  float mu = s * (1.f / 128.f);
  float var = s2v * (1.f / 128.f) - mu * mu;
  float rs = rsqrtf(var + 1e-5f);
  #pragma unroll
  for (int i = 0; i < 32; i++) {
    int c = sub + 4 * i;
    float v = (hs[r][c] - mu) * rs * gamma[c] + beta[c];
    h[rbase + r * 128 + c] = v;
    hs[r][c] = v;
  }
  __syncthreads();

  if (!t1) return;
  const int c = tid >> 1, half = tid & 1;
  u16 tmp[32];
  #pragma unroll
  for (int i = 0; i < 32; i++) tmp[i] = f2bf(hs[half * 32 + i][c]);
  const short8* tv = (const short8*)tmp;
  {
    long off = b * s1 + (long)(o1 + c) * 512 + n0 + half * 32;
    #pragma unroll
    for (int q = 0; q < 4; q++) *(short8*)&t1[off + q * 8] = tv[q];
  }
  if (t2) {
    long off = b * s2 + (long)(o2 + c) * 512 + n0 + half * 32;
    #pragma unroll
    for (int q = 0; q < 4; q++) *(short8*)&t2[off + q * 8] = tv[q];
  }
  if (t3) {
    long off = b * s3 + (long)(o3 + c) * 512 + n0 + half * 32;
    #pragma unroll
    for (int q = 0; q < 4; q++) *(short8*)&t3[off + q * 8] = tv[q];
  }
}

// ---------------------------------------------------------------------------
// x^T into layer-0 term-0 buffers (channels 0..15), both gates & cand copies.
__global__ __launch_bounds__(256) void xk(
    const float* __restrict__ x, long xb,
    u16* __restrict__ g, long sg, u16* __restrict__ c, long sc)
{
  int n = blockIdx.x * 256 + threadIdx.x;
  int ch = blockIdx.y;
  long b = blockIdx.z;
  u16 v = f2bf(x[b * xb + (long)n * 16 + ch]);
  g[b * sg + (long)ch * 512 + n] = v;
  c[b * sc + (long)ch * 512 + n] = v;
}

__global__ void cvt_bf16(const float* __restrict__ s, u16* __restrict__ d, int n) {
  int i = blockIdx.x * 256 + threadIdx.x;
  if (i < n) d[i] = f2bf(s[i]);
}
// W (Ksrc, Nout) fp32 -> Wt (Nout, Kpad) bf16, zero-pad k >= Ksrc.
__global__ void wt_cvt(const float* __restrict__ W, u16* __restrict__ Wt,
                       int Ksrc, int Kpad, int Nout) {
  long idx = (long)blockIdx.x * 256 + threadIdx.x;
  if (idx >= (long)Nout * Kpad) return;
  int o = (int)(idx / Kpad), k = (int)(idx % Kpad);
  Wt[idx] = f2bf(k < Ksrc ? W[(long)k * Nout + o] : 0.f);
}

// ---------------------------------------------------------------------------
extern "C" void kernel_launch(void* const* d_in, const int* in_sizes, int n_in,
                              void* d_out, int out_size, void* d_ws, size_t ws_size,
                              hipStream_t stream) {
  const float* x_seq = (const float*)d_in[0];
  const float* Tf  = (const float*)d_in[1];
  const float* Tb  = (const float*)d_in[2];
  const float* Wg0 = (const float*)d_in[3];
  const float* bg0 = (const float*)d_in[4];
  const float* Wc0 = (const float*)d_in[5];
  const float* bc0 = (const float*)d_in[6];
  const float* g0  = (const float*)d_in[7];
  const float* be0 = (const float*)d_in[8];
  const float* Wg1 = (const float*)d_in[9];
  const float* bg1 = (const float*)d_in[10];
  const float* Wc1 = (const float*)d_in[11];
  const float* bc1 = (const float*)d_in[12];
  const float* g1  = (const float*)d_in[13];
  const float* be1 = (const float*)d_in[14];

  constexpr int B = 32, T = 8, N = 512, F = 16, H = 128;
  constexpr long NB = (long)B * N;
  constexpr int C0 = 144, C1 = 256;
  constexpr long sT0 = (long)C0 * 512;   // layer-0 term0 per-batch stride (u16)
  constexpr long sT1 = (long)C1 * 512;
  constexpr long sSL0 = 880L * 512;      // 6*C0 + 16 pad rows
  constexpr long sSL1 = 1536L * 512;     // 6*C1

  char* p = (char*)d_ws;
  auto carve = [&](size_t bytes) { char* r = p; p += (bytes + 255) & ~(size_t)255; return r; };
  u16* t0g0 = (u16*)carve((size_t)B * sT0 * 2);
  u16* t0c0 = (u16*)carve((size_t)B * sT0 * 2);
  u16* t0g1 = (u16*)carve((size_t)B * sT1 * 2);
  u16* t0c1 = (u16*)carve((size_t)B * sT1 * 2);
  u16* sl   = (u16*)carve((size_t)B * sSL1 * 2);   // shared slices region (l1 size >= l0)
  float* ubuf = (float*)carve((size_t)NB * H * 4);
  float* cbuf = (float*)carve((size_t)NB * H * 4);
  u16* Tfb  = (u16*)carve(512L * 512 * 2);
  u16* Tbb  = (u16*)carve(512L * 512 * 2);
  u16* Wg0t = (u16*)carve(256L * 1024 * 2);
  u16* Wc0t = (u16*)carve(128L * 1024 * 2);
  u16* Wg1t = (u16*)carve(256L * 1792 * 2);
  u16* Wc1t = (u16*)carve(128L * 1792 * 2);

  float* h0 = (float*)d_out;
  float* h1 = h0 + NB * H;

  hipMemsetAsync(d_out, 0, (size_t)out_size * 4, stream);
  // zero term0 buffers (h=0 at t=0) and slices (incl. pad rows; avoids NaN * 0)
  hipMemsetAsync(t0g0, 0, (size_t)((char*)(sl + B * sSL1) - (char*)t0g0), stream);

  cvt_bf16<<<(512 * 512 + 255) / 256, 256, 0, stream>>>(Tf, Tfb, 512 * 512);
  cvt_bf16<<<(512 * 512 + 255) / 256, 256, 0, stream>>>(Tb, Tbb, 512 * 512);
  wt_cvt<<<(256 * 1024 + 255) / 256, 256, 0, stream>>>(Wg0, Wg0t, 1008, 1024, 256);
  wt_cvt<<<(128 * 1024 + 255) / 256, 256, 0, stream>>>(Wc0, Wc0t, 1008, 1024, 128);
  wt_cvt<<<(256 * 1792 + 255) / 256, 256, 0, stream>>>(Wg1, Wg1t, 1792, 1792, 256);
  wt_cvt<<<(128 * 1792 + 255) / 256, 256, 0, stream>>>(Wc1, Wc1t, 1792, 1792, 128);

  for (int t = 0; t < T; t++) {
    const float* xt = x_seq + (long)t * N * F;
    // ======== layer 0 ========
    xk<<<dim3(2, 16, B), 256, 0, stream>>>(xt, (long)T * N * F, t0g0, sT0, t0c0, sT0);
    {  // gates diffusion, M=144 (x+h)
      const long cs = 3L * C0 * 512;
      gemm_diff<48, 128, 1, 4><<<dim3(3, 4, 2 * B), 256, 0, stream>>>(t0g0, sT0, 0, sl, sSL0, cs, Tfb, Tbb);
      gemm_diff<48, 128, 1, 4><<<dim3(3, 4, 2 * B), 256, 0, stream>>>(sl, sSL0, cs, sl + (long)C0 * 512, sSL0, cs, Tfb, Tbb);
      gemm_diff<48, 128, 1, 4><<<dim3(3, 4, 2 * B), 256, 0, stream>>>(sl + (long)C0 * 512, sSL0, cs, sl + 2L * C0 * 512, sSL0, cs, Tfb, Tbb);
    }
    gemm_proj<128, 128, 2, 2, 1><<<dim3(4, 2, B), 256, 0, stream>>>(
        t0g0, sT0, C0, sl, sSL0, Wg0t, 1024, 1024, bg0, h0, t0c0 + 16L * 512, sT0, ubuf);
    {  // cand diffusion, M=128 (r*h half only; x-half reused from gates phase)
      const long cs = 3L * C0 * 512, hx = 16L * 512;
      gemm_diff<128, 128, 2, 2><<<dim3(1, 4, 2 * B), 256, 0, stream>>>(t0c0 + hx, sT0, 0, sl + hx, sSL0, cs, Tfb, Tbb);
      gemm_diff<128, 128, 2, 2><<<dim3(1, 4, 2 * B), 256, 0, stream>>>(sl + hx, sSL0, cs, sl + (long)C0 * 512 + hx, sSL0, cs, Tfb, Tbb);
      gemm_diff<128, 128, 2, 2><<<dim3(1, 4, 2 * B), 256, 0, stream>>>(sl + (long)C0 * 512 + hx, sSL0, cs, sl + 2L * C0 * 512 + hx, sSL0, cs, Tfb, Tbb);
    }
    gemm_proj<64, 128, 2, 2, 2><<<dim3(8, 1, B), 256, 0, stream>>>(
        t0c0, sT0, C0, sl, sSL0, Wc0t, 1024, 1024, bc0, nullptr, nullptr, 0, cbuf);
    gru_ln2<<<dim3(8, B), 256, 0, stream>>>(ubuf, cbuf, h0, g0, be0,
        t0g0, sT0, 16, t0g1, sT1, 0, t0c1, sT1, 0);
    // ======== layer 1 ========
    {  // gates diffusion, M=256 (h0+h1)
      const long cs = 3L * C1 * 512;
      gemm_diff<128, 128, 2, 2><<<dim3(2, 4, 2 * B), 256, 0, stream>>>(t0g1, sT1, 0, sl, sSL1, cs, Tfb, Tbb);
      gemm_diff<128, 128, 2, 2><<<dim3(2, 4, 2 * B), 256, 0, stream>>>(sl, sSL1, cs, sl + (long)C1 * 512, sSL1, cs, Tfb, Tbb);
      gemm_diff<128, 128, 2, 2><<<dim3(2, 4, 2 * B), 256, 0, stream>>>(sl + (long)C1 * 512, sSL1, cs, sl + 2L * C1 * 512, sSL1, cs, Tfb, Tbb);
    }
    gemm_proj<128, 128, 2, 2, 1><<<dim3(4, 2, B), 256, 0, stream>>>(
        t0g1, sT1, C1, sl, sSL1, Wg1t, 1792, 1792, bg1, h1, t0c1 + 128L * 512, sT1, ubuf);
    {  // cand diffusion, M=128 (r*h1 half)
      const long cs = 3L * C1 * 512, hx = 128L * 512;
      gemm_diff<128, 128, 2, 2><<<dim3(1, 4, 2 * B), 256, 0, stream>>>(t0c1 + hx, sT1, 0, sl + hx, sSL1, cs, Tfb, Tbb);
      gemm_diff<128, 128, 2, 2><<<dim3(1, 4, 2 * B), 256, 0, stream>>>(sl + hx, sSL1, cs, sl + (long)C1 * 512 + hx, sSL1, cs, Tfb, Tbb);
      gemm_diff<128, 128, 2, 2><<<dim3(1, 4, 2 * B), 256, 0, stream>>>(sl + (long)C1 * 512 + hx, sSL1, cs, sl + 2L * C1 * 512 + hx, sSL1, cs, Tfb, Tbb);
    }
    gemm_proj<64, 128, 2, 2, 2><<<dim3(8, 1, B), 256, 0, stream>>>(
        t0c1, sT1, C1, sl, sSL1, Wc1t, 1792, 1792, bc1, nullptr, nullptr, 0, cbuf);
    gru_ln2<<<dim3(8, B), 256, 0, stream>>>(ubuf, cbuf, h1, g1, be1,
        t0g1, sT1, 128, nullptr, 0, 0, nullptr, 0, 0);
  }
}

// Round 3
// 2472.838 us; speedup vs baseline: 2.5129x; 1.6219x over previous
//
#include <hip/hip_runtime.h>
#include <hip/hip_bf16.h>
#include <math.h>

typedef unsigned short u16;
typedef __attribute__((ext_vector_type(8))) short short8;
typedef __attribute__((ext_vector_type(4))) float f32x4;

__device__ __forceinline__ u16 f2bf(float f) {
  union { float f; unsigned u; } v; v.f = f;
  unsigned r = v.u + 0x7fffu + ((v.u >> 16) & 1u);
  return (u16)(r >> 16);
}

// async global->LDS, 16B/lane. LDS dest is wave-uniform base; HW adds lane*16.
__device__ __forceinline__ void glds16(const u16* g, u16* l) {
  __builtin_amdgcn_global_load_lds(
      (const __attribute__((address_space(1))) void*)g,
      (__attribute__((address_space(3))) void*)l, 16, 0, 0);
}

// ===========================================================================
// Diffusion: out[(b*512+node)*ldz + (1+tc)*C + coff0 + ch] =
//            sum_k Tpow[tc][node][k] * zT[ch][b][k]
// zT layout: [ch][b][node] (ch-outer, 16384 per ch row). grid.z = b*6 + tc.
// Optional dual-write of ch < Fdual into zdual (same cols, coff0 = 0).
// ===========================================================================
template<int BM, int BN, int WR, int WC>
__global__ __launch_bounds__(256) void gemm_diff(
    const u16* __restrict__ Tpow, const u16* __restrict__ zT,
    u16* __restrict__ zout, int ldz, int C, int coff0,
    u16* __restrict__ zdual, int Fdual)
{
  constexpr int BK = 32;
  constexpr int FM = BM / (WR * 16), FN = BN / (WC * 16);
  __shared__ u16 sm[(BM + BN) * BK];
  const int tid = threadIdx.x, lane = tid & 63, wid = tid >> 6;
  const int wr = wid / WC, wc = wid % WC;
  const int l15 = lane & 15, l4 = lane >> 4;
  const int m0 = blockIdx.x * BM;
  const int y0 = blockIdx.y * BN;
  const int b = blockIdx.z / 6, tc = blockIdx.z % 6;
  const u16* A = Tpow + (long)tc * 512 * 512;
  const u16* Bz = zT + (long)y0 * 16384 + b * 512;

  f32x4 acc[FM][FN] = {};
  for (int k0 = 0; k0 < 512; k0 += BK) {
    for (int s = tid; s < (BM + BN) * 4; s += 256) {
      const u16* gp;
      if (s < BM * 4) { int m = s >> 2, kc = s & 3; gp = A + (long)(m0 + m) * 512 + k0 + kc * 8; }
      else { int q = s - BM * 4; int n = q >> 2, kc = q & 3; gp = Bz + (long)n * 16384 + k0 + kc * 8; }
      glds16(gp, sm + (s - lane) * 8);
    }
    __syncthreads();
    short8 af[FM], bf[FN];
    #pragma unroll
    for (int i = 0; i < FM; i++)
      af[i] = *(const short8*)&sm[(wr * FM * 16 + i * 16 + l15) * BK + l4 * 8];
    #pragma unroll
    for (int j = 0; j < FN; j++)
      bf[j] = *(const short8*)&sm[BM * BK + (wc * FN * 16 + j * 16 + l15) * BK + l4 * 8];
    #pragma unroll
    for (int i = 0; i < FM; i++)
      #pragma unroll
      for (int j = 0; j < FN; j++)
        acc[i][j] = __builtin_amdgcn_mfma_f32_16x16x32_bf16(af[i], bf[j], acc[i][j], 0, 0, 0);
    __syncthreads();
  }

  const int tC = (1 + tc) * C;
  #pragma unroll
  for (int i = 0; i < FM; i++) {
    #pragma unroll
    for (int j = 0; j < FN; j++) {
      int node = m0 + wr * FM * 16 + i * 16 + l4 * 4;
      int ch = y0 + wc * FN * 16 + j * 16 + l15;
      #pragma unroll
      for (int rr = 0; rr < 4; rr++) {
        u16 v = f2bf(acc[i][j][rr]);
        long r = (long)b * 512 + node + rr;
        zout[r * ldz + tC + coff0 + ch] = v;
        if (Fdual && ch < Fdual) zdual[r * ldz + tC + ch] = v;
      }
    }
  }
}

// ===========================================================================
// Projection (giant-M): out(16384, Nout) = act(z(16384, K) @ W(Nout, K)^T + bias)
// MODE 1 (gates): n<128 -> rh = sig*hst -> zc[r*ldzc+Foff+n] (bf16) + zTc[n*16384+r];
//                 n>=128 -> ubuf[r*128+n-128] (fp32).
// MODE 2 (cand):  tanh -> outbuf[r*128+n] (fp32).
// ===========================================================================
template<int BM, int BN, int MODE>
__global__ __launch_bounds__(256) void gemm_proj(
    const u16* __restrict__ Az, int ldA,
    const u16* __restrict__ W, int K,
    const float* __restrict__ bias,
    const float* __restrict__ hst,
    u16* __restrict__ zc, int ldzc, int Foff,
    u16* __restrict__ zTc,
    float* __restrict__ outbuf)
{
  constexpr int BK = 32;
  constexpr int FM = BM / 32, FN = BN / 32;   // WR = WC = 2
  __shared__ u16 sm[(BM + BN) * BK];
  const int tid = threadIdx.x, lane = tid & 63, wid = tid >> 6;
  const int wr = wid >> 1, wc = wid & 1;
  const int l15 = lane & 15, l4 = lane >> 4;
  const int m0 = blockIdx.x * BM;
  const int n0 = blockIdx.y * BN;

  f32x4 acc[FM][FN] = {};
  for (int k0 = 0; k0 < K; k0 += BK) {
    for (int s = tid; s < (BM + BN) * 4; s += 256) {
      const u16* gp;
      if (s < BM * 4) { int m = s >> 2, kc = s & 3; gp = Az + (long)(m0 + m) * ldA + k0 + kc * 8; }
      else { int q = s - BM * 4; int n = q >> 2, kc = q & 3; gp = W + (long)(n0 + n) * K + k0 + kc * 8; }
      glds16(gp, sm + (s - lane) * 8);
    }
    __syncthreads();
    short8 af[FM], bf[FN];
    #pragma unroll
    for (int i = 0; i < FM; i++)
      af[i] = *(const short8*)&sm[(wr * FM * 16 + i * 16 + l15) * BK + l4 * 8];
    #pragma unroll
    for (int j = 0; j < FN; j++)
      bf[j] = *(const short8*)&sm[BM * BK + (wc * FN * 16 + j * 16 + l15) * BK + l4 * 8];
    #pragma unroll
    for (int i = 0; i < FM; i++)
      #pragma unroll
      for (int j = 0; j < FN; j++)
        acc[i][j] = __builtin_amdgcn_mfma_f32_16x16x32_bf16(af[i], bf[j], acc[i][j], 0, 0, 0);
    __syncthreads();
  }

  #pragma unroll
  for (int i = 0; i < FM; i++) {
    #pragma unroll
    for (int j = 0; j < FN; j++) {
      int mb = m0 + wr * FM * 16 + i * 16 + l4 * 4;
      int n = n0 + wc * FN * 16 + j * 16 + l15;
      #pragma unroll
      for (int rr = 0; rr < 4; rr++) {
        float v = acc[i][j][rr] + bias[n];
        long r = mb + rr;
        if constexpr (MODE == 1) {
          float g = 1.f / (1.f + expf(-v));
          if (n < 128) {
            float rh = g * hst[r * 128 + n];
            u16 hv = f2bf(rh);
            zc[r * ldzc + Foff + n] = hv;
            zTc[(long)n * 16384 + r] = hv;
          } else {
            outbuf[r * 128 + (n - 128)] = g;
          }
        } else {
          outbuf[r * 128 + n] = tanhf(v);
        }
      }
    }
  }
}

// ===========================================================================
// Fused GRU update + LayerNorm (H=128) + fan-out writes.
// Block: 64 nodes x 128 ch; grid (8, B).
// Row-major bf16 targets rm0..rm2 (ld, col-offset); ch-major targets cm0..cm1
// (layout [ch][b][node], row offset ro).
// ===========================================================================
__global__ __launch_bounds__(256) void gru_ln(
    const float* __restrict__ ub, const float* __restrict__ cd,
    float* __restrict__ h, const float* __restrict__ gamma, const float* __restrict__ beta,
    u16* __restrict__ rm0, int ld0, int co0,
    u16* __restrict__ rm1, int ld1, int co1,
    u16* __restrict__ rm2, int ld2, int co2,
    u16* __restrict__ cm0, int ro0,
    u16* __restrict__ cm1, int ro1)
{
  __shared__ float hs[64][132];
  const int tid = threadIdx.x;
  const long b = blockIdx.y;
  const int n0 = blockIdx.x * 64;
  const long rbase = (b * 512 + n0) * 128;

  #pragma unroll
  for (int i = 0; i < 32; i++) {
    int idx = tid + i * 256;
    float u = ub[rbase + idx];
    float cc = cd[rbase + idx];
    float hv = h[rbase + idx];
    hs[idx >> 7][idx & 127] = (1.f - u) * hv + u * cc;
  }
  __syncthreads();

  const int rw = tid >> 2, sub = tid & 3;
  float s = 0.f, s2v = 0.f;
  #pragma unroll
  for (int i = 0; i < 32; i++) {
    float v = hs[rw][sub + 4 * i];
    s += v; s2v += v * v;
  }
  s += __shfl_xor(s, 1); s2v += __shfl_xor(s2v, 1);
  s += __shfl_xor(s, 2); s2v += __shfl_xor(s2v, 2);
  float mu = s * (1.f / 128.f);
  float var = s2v * (1.f / 128.f) - mu * mu;
  float rs = rsqrtf(var + 1e-5f);
  #pragma unroll
  for (int i = 0; i < 32; i++) {
    int c = sub + 4 * i;
    float v = (hs[rw][c] - mu) * rs * gamma[c] + beta[c];
    h[rbase + rw * 128 + c] = v;
    hs[rw][c] = v;
  }
  __syncthreads();

  // row-major fan-out
  #pragma unroll
  for (int i = 0; i < 32; i++) {
    int idx = tid + i * 256;
    int node = idx >> 7, c = idx & 127;
    u16 v = f2bf(hs[node][c]);
    long r = b * 512 + n0 + node;
    rm0[r * ld0 + co0 + c] = v;
    if (rm1) rm1[r * ld1 + co1 + c] = v;
    if (rm2) rm2[r * ld2 + co2 + c] = v;
  }
  // ch-major fan-out
  const int c2 = tid >> 1, half = tid & 1;
  u16 tmp[32];
  #pragma unroll
  for (int i = 0; i < 32; i++) tmp[i] = f2bf(hs[half * 32 + i][c2]);
  const short8* tv = (const short8*)tmp;
  {
    long off = (long)(ro0 + c2) * 16384 + b * 512 + n0 + half * 32;
    #pragma unroll
    for (int q = 0; q < 4; q++) *(short8*)&cm0[off + q * 8] = tv[q];
  }
  if (cm1) {
    long off = (long)(ro1 + c2) * 16384 + b * 512 + n0 + half * 32;
    #pragma unroll
    for (int q = 0; q < 4; q++) *(short8*)&cm1[off + q * 8] = tv[q];
  }
}

// ===========================================================================
// small helpers
// ===========================================================================
// x_t -> z0g/z0c term0 cols[0,16) + z0Tg rows[0,16)
__global__ __launch_bounds__(256) void xk(
    const float* __restrict__ xs, int t,
    u16* __restrict__ z0g, u16* __restrict__ z0c, u16* __restrict__ z0Tg)
{
  int r = blockIdx.x * 256 + threadIdx.x;       // 0..16383 = b*512+n
  int b = r >> 9, n = r & 511;
  const float* src = xs + (((long)b * 8 + t) * 512 + n) * 16;
  u16 tmp[16];
  #pragma unroll
  for (int f = 0; f < 16; f++) tmp[f] = f2bf(src[f]);
  const short8* tv = (const short8*)tmp;
  *(short8*)&z0g[(long)r * 1024] = tv[0];
  *(short8*)&z0g[(long)r * 1024 + 8] = tv[1];
  *(short8*)&z0c[(long)r * 1024] = tv[0];
  *(short8*)&z0c[(long)r * 1024 + 8] = tv[1];
  #pragma unroll
  for (int f = 0; f < 16; f++) z0Tg[(long)f * 16384 + r] = tmp[f];
}

__global__ void zero_cols(u16* __restrict__ z, int ld, int c0) {  // zero 128 cols
  int idx = blockIdx.x * 256 + threadIdx.x;     // 16384*16
  int r = idx >> 4, s = idx & 15;
  short8 zz = {};
  *(short8*)&z[(long)r * ld + c0 + s * 8] = zz;
}

// T fp32 -> bf16 row-major (into Tpow slot) + bf16 transposed
__global__ void cvtT(const float* __restrict__ Tf, const float* __restrict__ Tb,
                     u16* __restrict__ Tpow, u16* __restrict__ TfT, u16* __restrict__ TbT)
{
  int idx = blockIdx.x * 256 + threadIdx.x;     // 262144
  int i = idx >> 9, j = idx & 511;
  const float* s = blockIdx.y ? Tb : Tf;
  u16* d = Tpow + (blockIdx.y ? 3 : 0) * 262144;
  u16* dT = blockIdx.y ? TbT : TfT;
  u16 v = f2bf(s[idx]);
  d[idx] = v;
  dT[(long)j * 512 + i] = v;
}

// small 512x512x512 bf16 GEMM for T powers: C = A @ Bt^T (two sets via grid.z)
__global__ __launch_bounds__(256) void gemm_pow(
    const u16* __restrict__ A0, const u16* __restrict__ B0, u16* __restrict__ C0,
    const u16* __restrict__ A1, const u16* __restrict__ B1, u16* __restrict__ C1)
{
  constexpr int BM = 64, BN = 64, BK = 32;
  __shared__ u16 sm[(BM + BN) * BK];
  const int tid = threadIdx.x, lane = tid & 63, wid = tid >> 6;
  const int wr = wid >> 1, wc = wid & 1;
  const int l15 = lane & 15, l4 = lane >> 4;
  const int m0 = blockIdx.x * BM, n0 = blockIdx.y * BN;
  const u16* A = blockIdx.z ? A1 : A0;
  const u16* Bt = blockIdx.z ? B1 : B0;
  u16* Cc = blockIdx.z ? C1 : C0;

  f32x4 acc[2][2] = {};
  for (int k0 = 0; k0 < 512; k0 += BK) {
    for (int s = tid; s < (BM + BN) * 4; s += 256) {
      const u16* gp;
      if (s < BM * 4) { int m = s >> 2, kc = s & 3; gp = A + (long)(m0 + m) * 512 + k0 + kc * 8; }
      else { int q = s - BM * 4; int n = q >> 2, kc = q & 3; gp = Bt + (long)(n0 + n) * 512 + k0 + kc * 8; }
      glds16(gp, sm + (s - lane) * 8);
    }
    __syncthreads();
    short8 af[2], bf[2];
    #pragma unroll
    for (int i = 0; i < 2; i++)
      af[i] = *(const short8*)&sm[(wr * 32 + i * 16 + l15) * BK + l4 * 8];
    #pragma unroll
    for (int j = 0; j < 2; j++)
      bf[j] = *(const short8*)&sm[BM * BK + (wc * 32 + j * 16 + l15) * BK + l4 * 8];
    #pragma unroll
    for (int i = 0; i < 2; i++)
      #pragma unroll
      for (int j = 0; j < 2; j++)
        acc[i][j] = __builtin_amdgcn_mfma_f32_16x16x32_bf16(af[i], bf[j], acc[i][j], 0, 0, 0);
    __syncthreads();
  }
  #pragma unroll
  for (int i = 0; i < 2; i++)
    #pragma unroll
    for (int j = 0; j < 2; j++) {
      int mb = m0 + wr * 32 + i * 16 + l4 * 4;
      int n = n0 + wc * 32 + j * 16 + l15;
      #pragma unroll
      for (int rr = 0; rr < 4; rr++)
        Cc[(long)(mb + rr) * 512 + n] = f2bf(acc[i][j][rr]);
    }
}

// W (Ksrc, Nout) fp32 -> Wt (Nout, Kpad) bf16, zero-pad k >= Ksrc.
__global__ void wt_cvt(const float* __restrict__ W, u16* __restrict__ Wt,
                       int Ksrc, int Kpad, int Nout) {
  long idx = (long)blockIdx.x * 256 + threadIdx.x;
  if (idx >= (long)Nout * Kpad) return;
  int o = (int)(idx / Kpad), k = (int)(idx % Kpad);
  Wt[idx] = f2bf(k < Ksrc ? W[(long)k * Nout + o] : 0.f);
}

// ===========================================================================
extern "C" void kernel_launch(void* const* d_in, const int* in_sizes, int n_in,
                              void* d_out, int out_size, void* d_ws, size_t ws_size,
                              hipStream_t stream) {
  const float* x_seq = (const float*)d_in[0];
  const float* Tf  = (const float*)d_in[1];
  const float* Tb  = (const float*)d_in[2];
  const float* Wg0 = (const float*)d_in[3];
  const float* bg0 = (const float*)d_in[4];
  const float* Wc0 = (const float*)d_in[5];
  const float* bc0 = (const float*)d_in[6];
  const float* g0  = (const float*)d_in[7];
  const float* be0 = (const float*)d_in[8];
  const float* Wg1 = (const float*)d_in[9];
  const float* bg1 = (const float*)d_in[10];
  const float* Wc1 = (const float*)d_in[11];
  const float* bc1 = (const float*)d_in[12];
  const float* g1  = (const float*)d_in[13];
  const float* be1 = (const float*)d_in[14];

  constexpr int B = 32, T = 8;
  constexpr long M = 16384;              // B*512 giant-M rows

  char* p = (char*)d_ws;
  auto carve = [&](size_t bytes) { char* r = p; p += (bytes + 255) & ~(size_t)255; return r; };
  u16* z0g  = (u16*)carve(M * 1024 * 2);
  u16* z0c  = (u16*)carve(M * 1024 * 2);
  u16* z1g  = (u16*)carve(M * 1792 * 2);
  u16* z1c  = (u16*)carve(M * 1792 * 2);
  u16* z0Tg = (u16*)carve(144L * M * 2);
  u16* z0Tc = (u16*)carve(128L * M * 2);
  u16* z1Tg = (u16*)carve(256L * M * 2);
  u16* z1Tc = (u16*)carve(128L * M * 2);
  float* ubuf = (float*)carve(M * 128 * 4);
  float* cbuf = (float*)carve(M * 128 * 4);
  u16* Tpow = (u16*)carve(6L * 512 * 512 * 2);   // Tf,Tf2,Tf3,Tb,Tb2,Tb3
  u16* TfT  = (u16*)carve(512L * 512 * 2);
  u16* TbT  = (u16*)carve(512L * 512 * 2);
  u16* Wg0t = (u16*)carve(256L * 1024 * 2);
  u16* Wc0t = (u16*)carve(128L * 1024 * 2);
  u16* Wg1t = (u16*)carve(256L * 1792 * 2);
  u16* Wc1t = (u16*)carve(128L * 1792 * 2);

  float* h0 = (float*)d_out;
  float* h1 = h0 + M * 128;

  // per-launch init: h=0; h-parts of term0 (row-major + ch-major mirrors) = 0
  hipMemsetAsync(d_out, 0, (size_t)out_size * 4, stream);
  zero_cols<<<1024, 256, 0, stream>>>(z0g, 1024, 16);
  zero_cols<<<1024, 256, 0, stream>>>(z1g, 1792, 128);
  hipMemsetAsync(z0Tg + 16L * M, 0, 128L * M * 2, stream);
  hipMemsetAsync(z1Tg + 128L * M, 0, 128L * M * 2, stream);

  // weights / T powers
  cvtT<<<dim3(1024, 2), 256, 0, stream>>>(Tf, Tb, Tpow, TfT, TbT);
  gemm_pow<<<dim3(8, 8, 2), 256, 0, stream>>>(
      Tpow, TfT, Tpow + 1L * 262144, Tpow + 3L * 262144, TbT, Tpow + 4L * 262144);
  gemm_pow<<<dim3(8, 8, 2), 256, 0, stream>>>(
      Tpow + 1L * 262144, TfT, Tpow + 2L * 262144, Tpow + 4L * 262144, TbT, Tpow + 5L * 262144);
  wt_cvt<<<(256 * 1024 + 255) / 256, 256, 0, stream>>>(Wg0, Wg0t, 1008, 1024, 256);
  wt_cvt<<<(128 * 1024 + 255) / 256, 256, 0, stream>>>(Wc0, Wc0t, 1008, 1024, 128);
  wt_cvt<<<(256 * 1792 + 255) / 256, 256, 0, stream>>>(Wg1, Wg1t, 1792, 1792, 256);
  wt_cvt<<<(128 * 1792 + 255) / 256, 256, 0, stream>>>(Wc1, Wc1t, 1792, 1792, 128);

  for (int t = 0; t < T; t++) {
    // ======== layer 0 (C=144, Kpad=1024) ========
    xk<<<64, 256, 0, stream>>>(x_seq, t, z0g, z0c, z0Tg);
    gemm_diff<128, 48, 4, 1><<<dim3(4, 3, 6 * B), 256, 0, stream>>>(
        Tpow, z0Tg, z0g, 1024, 144, 0, z0c, 16);
    gemm_proj<64, 64, 1><<<dim3(256, 4), 256, 0, stream>>>(
        z0g, 1024, Wg0t, 1024, bg0, h0, z0c, 1024, 16, z0Tc, ubuf);
    gemm_diff<128, 64, 2, 2><<<dim3(4, 2, 6 * B), 256, 0, stream>>>(
        Tpow, z0Tc, z0c, 1024, 144, 16, nullptr, 0);
    gemm_proj<64, 64, 2><<<dim3(256, 2), 256, 0, stream>>>(
        z0c, 1024, Wc0t, 1024, bc0, nullptr, nullptr, 0, 0, nullptr, cbuf);
    gru_ln<<<dim3(8, B), 256, 0, stream>>>(ubuf, cbuf, h0, g0, be0,
        z0g, 1024, 16, z1g, 1792, 0, z1c, 1792, 0, z0Tg, 16, z1Tg, 0);
    // ======== layer 1 (C=256, Kpad=1792) ========
    gemm_diff<128, 64, 2, 2><<<dim3(4, 4, 6 * B), 256, 0, stream>>>(
        Tpow, z1Tg, z1g, 1792, 256, 0, z1c, 128);
    gemm_proj<64, 64, 1><<<dim3(256, 4), 256, 0, stream>>>(
        z1g, 1792, Wg1t, 1792, bg1, h1, z1c, 1792, 128, z1Tc, ubuf);
    gemm_diff<128, 64, 2, 2><<<dim3(4, 2, 6 * B), 256, 0, stream>>>(
        Tpow, z1Tc, z1c, 1792, 256, 128, nullptr, 0);
    gemm_proj<64, 64, 2><<<dim3(256, 2), 256, 0, stream>>>(
        z1c, 1792, Wc1t, 1792, bc1, nullptr, nullptr, 0, 0, nullptr, cbuf);
    gru_ln<<<dim3(8, B), 256, 0, stream>>>(ubuf, cbuf, h1, g1, be1,
        z1g, 1792, 128, nullptr, 0, 0, nullptr, 0, 0, z1Tg, 128, nullptr, 0);
  }
}